// Round 5
// baseline (107.416 us; speedup 1.0000x reference)
//
#include <hip/hip_runtime.h>

// STAttn fused v4: B,T,N,D = 32,32,64,512; H=64; OUT=256.
// 1024 blocks (1 bt) x 512 threads (8 waves). Waves = (nh, jh, kh).
// k-mapping: iteration kt covers contiguous cols [kt*64, kt*64+64);
//   kh=0 waves consume cols [kt*64, +32), kh=1 waves [kt*64+32, +32).
// Staging: depth-4 register pipeline (4 slots x 16 floats/thread); threads
//   0-255 stage x, 256-511 stage ue_w; loads stay in flight across barriers
//   (T14 issue-early/write-late), k-loop itself is pure LDS+MFMA.
// bf16 hi/lo split, 3x mfma_f32_32x32x16_bf16 per 16-k step.
// Phase 2: e = lrelu(h+bias)@w_w (w_b dropped); softmax over N.
// Phase 3: pooling from global (L2/L3-resident). Phase 4: fc in fp32 VALU.

typedef __attribute__((ext_vector_type(8)))  short bf16x8;
typedef __attribute__((ext_vector_type(16))) float f32x16;

// fp32 -> bf16 hi (trunc) + lo (residual, trunc); alo*blo term (~2^-16) dropped.
__device__ __forceinline__ void split8t(const float* __restrict__ v,
                                        bf16x8& h8, bf16x8& l8) {
#pragma unroll
    for (int i = 0; i < 8; ++i) {
        const unsigned u = __float_as_uint(v[i]);
        h8[i] = (short)(u >> 16);
        const float hf = __uint_as_float(u & 0xFFFF0000u);
        l8[i] = (short)(__float_as_uint(v[i] - hf) >> 16);
    }
}

__global__ __launch_bounds__(512, 4) void stattn_all(
    const float* __restrict__ inp,    // [1024][64][512]
    const float* __restrict__ ue_w,   // [64][512]
    const float* __restrict__ ue_b,   // [64]
    const float* __restrict__ be,     // [64]
    const float* __restrict__ w_w,    // [64]
    const float* __restrict__ fc1_w,  // [256][512]
    const float* __restrict__ fc1_b,  // [256]
    float* __restrict__ out)          // [1024][256]
{
    // [kh][c(8-col group)][row][8] shorts; frag reads are 16B/lane.
    __shared__ __align__(16) short xh[2][4][64][8];
    __shared__ __align__(16) short xl[2][4][64][8];
    __shared__ __align__(16) short wh[2][4][64][8];
    __shared__ __align__(16) short wl[2][4][64][8];
    __shared__ float ep_s[2][64];
    __shared__ float a_s[64];
    __shared__ __align__(16) float attr_s[512];

    const int tid = threadIdx.x;
    const int wv  = tid >> 6;
    const int l   = tid & 63;
    const int l31 = l & 31;
    const int hi5 = l >> 5;
    const int kh  = wv & 1;         // k sub-band within each 64-col tile
    const int jh  = (wv >> 1) & 1;  // hidden half
    const int nh  = wv >> 2;        // token half

    const float* __restrict__ xg = inp + (size_t)blockIdx.x * (64 * 512);

    // ---- staging role: threads 0-255 stage x, 256-511 stage ue_w ----
    const int s_w   = tid >> 8;
    const int st    = tid & 255;
    const int s_row = st >> 2;
    const int s_sc  = st & 3;
    const float* __restrict__ s_base =
        (s_w ? ue_w : xg) + s_row * 512 + s_sc * 8;

    short* const hbase = (s_w ? &wh[0][0][0][0] : &xh[0][0][0][0]);
    short* const lbase = (s_w ? &wl[0][0][0][0] : &xl[0][0][0][0]);
    const int wo0 = s_sc * 512 + s_row * 8;         // kh=0 plane
    const int wo1 = 2048 + s_sc * 512 + s_row * 8;  // kh=1 plane

    __align__(16) float sl[4][16];   // 4-slot register pipeline

    f32x16 acc = {};

    // prologue: issue 4 iterations of loads (16 float4 in flight/thread)
#pragma unroll
    for (int kt = 0; kt < 4; ++kt) {
        const float4* p = reinterpret_cast<const float4*>(s_base + kt * 64);
        *reinterpret_cast<float4*>(&sl[kt][0])  = p[0];
        *reinterpret_cast<float4*>(&sl[kt][4])  = p[1];
        *reinterpret_cast<float4*>(&sl[kt][8])  = p[8];   // +32 cols
        *reinterpret_cast<float4*>(&sl[kt][12]) = p[9];
    }

#pragma unroll
    for (int kt = 0; kt < 8; ++kt) {
        float* const cur = sl[kt & 3];
        __syncthreads();  // previous tile's readers done
        {
            bf16x8 h8, l8;
            split8t(&cur[0], h8, l8);           // cols kt*64 + s_sc*8 (kh=0)
            *reinterpret_cast<bf16x8*>(hbase + wo0) = h8;
            *reinterpret_cast<bf16x8*>(lbase + wo0) = l8;
            split8t(&cur[8], h8, l8);           // cols kt*64+32+s_sc*8 (kh=1)
            *reinterpret_cast<bf16x8*>(hbase + wo1) = h8;
            *reinterpret_cast<bf16x8*>(lbase + wo1) = l8;
        }
        if (kt < 4) {  // refill freed slot for iteration kt+4
            const float4* p = reinterpret_cast<const float4*>(s_base + (kt + 4) * 64);
            *reinterpret_cast<float4*>(&cur[0])  = p[0];
            *reinterpret_cast<float4*>(&cur[4])  = p[1];
            *reinterpret_cast<float4*>(&cur[8])  = p[8];
            *reinterpret_cast<float4*>(&cur[12]) = p[9];
        }
        __syncthreads();
#pragma unroll
        for (int s = 0; s < 2; ++s) {
            const int c  = 2 * s + hi5;
            const int ar = nh * 32 + l31;
            const int br = jh * 32 + l31;
            const bf16x8 ah = *reinterpret_cast<const bf16x8*>(&xh[kh][c][ar][0]);
            const bf16x8 al = *reinterpret_cast<const bf16x8*>(&xl[kh][c][ar][0]);
            const bf16x8 bh = *reinterpret_cast<const bf16x8*>(&wh[kh][c][br][0]);
            const bf16x8 bl = *reinterpret_cast<const bf16x8*>(&wl[kh][c][br][0]);
            acc = __builtin_amdgcn_mfma_f32_32x32x16_bf16(ah, bh, acc, 0, 0, 0);
            acc = __builtin_amdgcn_mfma_f32_32x32x16_bf16(al, bh, acc, 0, 0, 0);
            acc = __builtin_amdgcn_mfma_f32_32x32x16_bf16(ah, bl, acc, 0, 0, 0);
        }
    }

    // ---- combine kh partials (reuse staging LDS as fp32 scratch) ----
    __syncthreads();
    {
        const int tile = nh * 2 + jh;
        float* hp = (tile < 2) ? reinterpret_cast<float*>(xh)
                               : reinterpret_cast<float*>(xl);
        const int toff = (tile & 1) * 1024 + l;
        if (kh == 1) {
#pragma unroll
            for (int r = 0; r < 16; ++r) hp[toff + r * 64] = acc[r];
        }
        __syncthreads();
        if (kh == 0) {
#pragma unroll
            for (int r = 0; r < 16; ++r) acc[r] += hp[toff + r * 64];
            // phase 2: bias + lrelu + dot w_w
            // C/D layout: col j = l&31, row n = (r&3) + 8*(r>>2) + 4*(l>>5)
            const int j = jh * 32 + l31;
            const float bias = ue_b[j] + be[j];
            const float ww   = w_w[j];
#pragma unroll
            for (int r = 0; r < 16; ++r) {
                float hv = acc[r] + bias;
                hv = hv > 0.f ? hv : 0.2f * hv;
                float p = hv * ww;
                p += __shfl_xor(p, 1);
                p += __shfl_xor(p, 2);
                p += __shfl_xor(p, 4);
                p += __shfl_xor(p, 8);
                p += __shfl_xor(p, 16);
                if (l31 == 0) {
                    const int nr = (r & 3) + 8 * (r >> 2) + 4 * hi5;
                    ep_s[jh][nh * 32 + nr] = p;
                }
            }
        }
    }
    __syncthreads();

    // ---- softmax over 64 tokens ----
    {
        const float v = ep_s[0][l] + ep_s[1][l];
        float mx = v;
#pragma unroll
        for (int off = 32; off >= 1; off >>= 1) mx = fmaxf(mx, __shfl_xor(mx, off));
        const float ex = expf(v - mx);
        float sm = ex;
#pragma unroll
        for (int off = 32; off >= 1; off >>= 1) sm += __shfl_xor(sm, off);
        if (wv == 0) a_s[l] = ex / sm;
    }
    __syncthreads();

    // ---- phase 3: pooling, thread d = tid (x L2/L3-resident) ----
    {
        const int d = tid;
        float s = 0.f;
#pragma unroll 8
        for (int n = 0; n < 64; ++n) s = fmaf(a_s[n], xg[n * 512 + d], s);
        attr_s[d] = s;
    }
    __syncthreads();

    // ---- phase 4: fc in fp32 VALU; 2 threads per output o ----
    {
        const int o  = tid >> 1;
        const int ks = tid & 1;
        const float* __restrict__ wrow = fc1_w + o * 512 + ks * 256;
        const float* __restrict__ ap   = attr_s + ks * 256;
        float s0 = 0.f, s1 = 0.f, s2 = 0.f, s3 = 0.f;
#pragma unroll 8
        for (int i = 0; i < 64; ++i) {
            const float4 w4 = *reinterpret_cast<const float4*>(&wrow[i * 4]);
            const float4 a4 = *reinterpret_cast<const float4*>(&ap[i * 4]);
            s0 = fmaf(a4.x, w4.x, s0);
            s1 = fmaf(a4.y, w4.y, s1);
            s2 = fmaf(a4.z, w4.z, s2);
            s3 = fmaf(a4.w, w4.w, s3);
        }
        float p = (s0 + s1) + (s2 + s3);
        p += __shfl_xor(p, 1);
        if (ks == 0) {
            const int bt  = blockIdx.x;
            const int row = (bt & 31) * 32 + (bt >> 5);  // t*B + b
            out[row * 256 + o] = p + fc1_b[o];
        }
    }
}

extern "C" void kernel_launch(void* const* d_in, const int* in_sizes, int n_in,
                              void* d_out, int out_size, void* d_ws, size_t ws_size,
                              hipStream_t stream) {
    const float* inp   = (const float*)d_in[0];
    const float* ue_w  = (const float*)d_in[1];
    const float* ue_b  = (const float*)d_in[2];
    const float* be    = (const float*)d_in[3];
    const float* w_w   = (const float*)d_in[4];
    // d_in[5] = w_b: unused (softmax invariant to constant shift)
    const float* fc1_w = (const float*)d_in[6];
    const float* fc1_b = (const float*)d_in[7];
    float* out = (float*)d_out;

    stattn_all<<<1024, 512, 0, stream>>>(inp, ue_w, ue_b, be, w_w, fc1_w, fc1_b, out);
}

// Round 6
// 74.303 us; speedup vs baseline: 1.4456x; 1.4456x over previous
//
#include <hip/hip_runtime.h>

// STAttn v5: B,T,N,D=32,32,64,512; H=64; OUT=256.
// A-kernel (1024 blocks x 512 thr): per bt: h=lrelu(x@ue_w^T+b); e=h@w_w;
//   a=softmax(e); attr=sum a_n x_n. x & ue_w staged fp32->LDS via
//   global_load_lds (16B), XOR-swizzled (chunk^row&7, pre-swizzled source),
//   double-buffered, ONE raw barrier per k-tile, vmcnt waited explicitly.
//   bf16 hi/lo split at fragment read; 3x mfma_f32_32x32x16_bf16.
// MODE 0 (ws_size >= 2MB): attr -> d_ws; B-kernel does fc (fc1_w read once-ish).
// MODE 1 fallback: fc in-block (fc1_w redundant) — no d_ws use.

typedef __attribute__((ext_vector_type(8)))  short bf16x8;
typedef __attribute__((ext_vector_type(16))) float f32x16;

#define AS3(p) ((__attribute__((address_space(3))) void*)(p))
#define AS1(p) ((const __attribute__((address_space(1))) void*)(p))
#define WAITVM0() asm volatile("s_waitcnt vmcnt(0)" ::: "memory")
#define SCHEDB()  __builtin_amdgcn_sched_barrier(0)

// fp32 -> bf16 hi (trunc) + lo (residual, trunc); alo*blo (~2^-16) dropped.
__device__ __forceinline__ void split8t(const float* __restrict__ v,
                                        bf16x8& h8, bf16x8& l8) {
#pragma unroll
    for (int i = 0; i < 8; ++i) {
        const unsigned u = __float_as_uint(v[i]);
        h8[i] = (short)(u >> 16);
        const float hf = __uint_as_float(u & 0xFFFF0000u);
        l8[i] = (short)(__float_as_uint(v[i] - hf) >> 16);
    }
}

template<int MODE>
__global__ __launch_bounds__(512, 4) void stattn_main(
    const float* __restrict__ inp,    // [1024][64][512]
    const float* __restrict__ ue_w,   // [64][512]
    const float* __restrict__ ue_b,   // [64]
    const float* __restrict__ be,     // [64]
    const float* __restrict__ w_w,    // [64]
    const float* __restrict__ fc1_w,  // [256][512] (MODE 1 only)
    const float* __restrict__ fc1_b,  // [256]      (MODE 1 only)
    float* __restrict__ dst)          // MODE 0: attr[1024][512]; MODE 1: out
{
    // fp32 tiles [64 rows][64 cols], row = 256B; chunk (8 floats = 32B)
    // stored at physical chunk = logical ^ (row&7). 16KB each, double-buffered.
    __shared__ __align__(16) float xb[2][64 * 64];
    __shared__ __align__(16) float wb[2][64 * 64];
    __shared__ float ep_s[2][64];
    __shared__ float a_s[64];
    __shared__ __align__(16) float attr_s[512];

    const int tid = threadIdx.x;
    const int wv  = tid >> 6;
    const int l   = tid & 63;
    const int l31 = l & 31;
    const int hi5 = l >> 5;
    const int kh  = wv & 1;         // K half within 64-col tile
    const int jh  = (wv >> 1) & 1;  // hidden half
    const int nh  = wv >> 2;        // token half
    const float* __restrict__ xg = inp + (size_t)blockIdx.x * (64 * 512);

    // staging: wave wv stages rows [wv*8, wv*8+8) of both tiles, 2 instrs each
    // (4 rows/instr, 1KB linear LDS). Source col pre-swizzled so linear LDS
    // dest => physical chunk c holds logical chunk c^(row&7) (rule #21).
    const int r_a  = wv * 8 + (l >> 4);
    const int r_b  = r_a + 4;
    const int cph  = (l & 15) >> 1;
    const int hfl  = l & 1;
    const int colA = (cph ^ (r_a & 7)) * 8 + hfl * 4;
    const int colB = (cph ^ (r_b & 7)) * 8 + hfl * 4;
    const float* __restrict__ gxa = xg   + r_a * 512 + colA;
    const float* __restrict__ gxb = xg   + r_b * 512 + colB;
    const float* __restrict__ gwa = ue_w + r_a * 512 + colA;
    const float* __restrict__ gwb = ue_w + r_b * 512 + colB;

#define STAGE(buf, kt) do {                                                          \
    __builtin_amdgcn_global_load_lds(AS1(gxa + (kt) * 64),                           \
        AS3((char*)&xb[buf][0] + (wv * 8) * 256), 16, 0, 0);                         \
    __builtin_amdgcn_global_load_lds(AS1(gxb + (kt) * 64),                           \
        AS3((char*)&xb[buf][0] + (wv * 8 + 4) * 256), 16, 0, 0);                     \
    __builtin_amdgcn_global_load_lds(AS1(gwa + (kt) * 64),                           \
        AS3((char*)&wb[buf][0] + (wv * 8) * 256), 16, 0, 0);                         \
    __builtin_amdgcn_global_load_lds(AS1(gwb + (kt) * 64),                           \
        AS3((char*)&wb[buf][0] + (wv * 8 + 4) * 256), 16, 0, 0);                     \
} while (0)

    f32x16 acc = {};
    STAGE(0, 0);

    const int arow = nh * 32 + l31;
    const int brow = jh * 32 + l31;

#pragma unroll
    for (int kt = 0; kt < 8; ++kt) {
        const int cur = kt & 1;
        WAITVM0();                       // my stage for 'cur' landed
        SCHEDB();
        __builtin_amdgcn_s_barrier();    // everyone's 'cur' landed; prev readers done
        SCHEDB();
        if (kt < 7) STAGE(cur ^ 1, kt + 1);  // DMA next tile under compute
        const float* __restrict__ xrow = &xb[cur][arow * 64];
        const float* __restrict__ wrow = &wb[cur][brow * 64];
#pragma unroll
        for (int s = 0; s < 2; ++s) {
            const int ck = kh * 4 + 2 * s + hi5;       // logical chunk 0..7
            const int pa = (ck ^ (arow & 7)) * 8;
            const int pb = (ck ^ (brow & 7)) * 8;
            float av[8], bv[8];
            *reinterpret_cast<float4*>(&av[0]) = *reinterpret_cast<const float4*>(&xrow[pa]);
            *reinterpret_cast<float4*>(&av[4]) = *reinterpret_cast<const float4*>(&xrow[pa + 4]);
            *reinterpret_cast<float4*>(&bv[0]) = *reinterpret_cast<const float4*>(&wrow[pb]);
            *reinterpret_cast<float4*>(&bv[4]) = *reinterpret_cast<const float4*>(&wrow[pb + 4]);
            bf16x8 ah, al, bh, bl;
            split8t(av, ah, al);
            split8t(bv, bh, bl);
            acc = __builtin_amdgcn_mfma_f32_32x32x16_bf16(ah, bh, acc, 0, 0, 0);
            acc = __builtin_amdgcn_mfma_f32_32x32x16_bf16(al, bh, acc, 0, 0, 0);
            acc = __builtin_amdgcn_mfma_f32_32x32x16_bf16(ah, bl, acc, 0, 0, 0);
        }
    }

    // ---- combine kh partials in xb[0] (16KB = 4 tiles x 1024 floats) ----
    __syncthreads();   // all k-loop reads done
    {
        float* hp = &xb[0][0];
        const int toff = (nh * 2 + jh) * 1024 + l;
        if (kh == 1) {
#pragma unroll
            for (int r = 0; r < 16; ++r) hp[toff + r * 64] = acc[r];
        }
        __syncthreads();
        if (kh == 0) {
#pragma unroll
            for (int r = 0; r < 16; ++r) acc[r] += hp[toff + r * 64];
            // phase 2: bias + lrelu + dot w_w (w_b dropped: softmax-shift-inv)
            // C/D layout: col j = l&31, row n = (r&3) + 8*(r>>2) + 4*(l>>5)
            const int j = jh * 32 + l31;
            const float bias = ue_b[j] + be[j];
            const float ww   = w_w[j];
#pragma unroll
            for (int r = 0; r < 16; ++r) {
                float hv = acc[r] + bias;
                hv = hv > 0.f ? hv : 0.2f * hv;
                float p = hv * ww;
                p += __shfl_xor(p, 1);
                p += __shfl_xor(p, 2);
                p += __shfl_xor(p, 4);
                p += __shfl_xor(p, 8);
                p += __shfl_xor(p, 16);
                if (l31 == 0) {
                    const int nr = (r & 3) + 8 * (r >> 2) + 4 * hi5;
                    ep_s[jh][nh * 32 + nr] = p;
                }
            }
        }
    }
    __syncthreads();

    // ---- softmax over 64 tokens ----
    {
        const float v = ep_s[0][l] + ep_s[1][l];
        float mx = v;
#pragma unroll
        for (int off = 32; off >= 1; off >>= 1) mx = fmaxf(mx, __shfl_xor(mx, off));
        const float ex = expf(v - mx);
        float sm = ex;
#pragma unroll
        for (int off = 32; off >= 1; off >>= 1) sm += __shfl_xor(sm, off);
        if (wv == 0) a_s[l] = ex / sm;
    }
    __syncthreads();

    // ---- pooling: thread d = tid (x re-read from global, L2/L3-resident) ----
    {
        const int d = tid;
        float s = 0.f;
#pragma unroll 8
        for (int n = 0; n < 64; ++n) s = fmaf(a_s[n], xg[n * 512 + d], s);
        if (MODE == 0) {
            dst[(size_t)blockIdx.x * 512 + d] = s;   // attr -> d_ws
        } else {
            attr_s[d] = s;
        }
    }

    if (MODE == 1) {
        __syncthreads();
        // fc in-block (fallback): 2 threads per output o
        const int o  = tid >> 1;
        const int ks = tid & 1;
        const float* __restrict__ wr = fc1_w + o * 512 + ks * 256;
        const float* __restrict__ ap = attr_s + ks * 256;
        float s0 = 0.f, s1 = 0.f, s2 = 0.f, s3 = 0.f;
#pragma unroll 8
        for (int i = 0; i < 64; ++i) {
            const float4 w4 = *reinterpret_cast<const float4*>(&wr[i * 4]);
            const float4 a4 = *reinterpret_cast<const float4*>(&ap[i * 4]);
            s0 = fmaf(a4.x, w4.x, s0);
            s1 = fmaf(a4.y, w4.y, s1);
            s2 = fmaf(a4.z, w4.z, s2);
            s3 = fmaf(a4.w, w4.w, s3);
        }
        float p = (s0 + s1) + (s2 + s3);
        p += __shfl_xor(p, 1);
        if (ks == 0) {
            const int bt  = blockIdx.x;
            const int row = (bt & 31) * 32 + (bt >> 5);
            dst[row * 256 + o] = p + fc1_b[o];
        }
    }
#undef STAGE
}

// fc GEMM: out[(bt&31)*32+(bt>>5)][o] = attr[bt] . fc1_w[o] + fc1_b[o]
// grid (32,8): block = 32 bt x 32 o; fc1_w total traffic = 16MB.
__global__ __launch_bounds__(256, 2) void stattn_fc2(
    const float* __restrict__ attr,   // [1024][512] (d_ws)
    const float* __restrict__ fc1_w,  // [256][512]
    const float* __restrict__ fc1_b,  // [256]
    float* __restrict__ out)          // [1024][256]
{
    __shared__ __align__(16) float at[32][516];
    const int tid = threadIdx.x;
    const int bm  = blockIdx.x;   // bt tile
    const int bn  = blockIdx.y;   // o tile

    {   // stage attr tile 32x512
        const int row = tid >> 3;
        const int seg = tid & 7;
        const float* __restrict__ src = attr + (size_t)(bm * 32 + row) * 512 + seg * 64;
#pragma unroll
        for (int q = 0; q < 16; ++q)
            *reinterpret_cast<float4*>(&at[row][seg * 64 + q * 4]) =
                *reinterpret_cast<const float4*>(&src[q * 4]);
    }
    __syncthreads();

    const int tx = tid & 31;   // o within tile
    const int ty = tid >> 5;   // bt quad
    const int o  = bn * 32 + tx;
    const float* __restrict__ wr = fc1_w + (size_t)o * 512;
    float s0 = 0.f, s1 = 0.f, s2 = 0.f, s3 = 0.f;
#pragma unroll 4
    for (int kq = 0; kq < 128; ++kq) {
        const float4 w4 = *reinterpret_cast<const float4*>(&wr[kq * 4]);
        const float4 a0 = *reinterpret_cast<const float4*>(&at[ty * 4 + 0][kq * 4]);
        const float4 a1 = *reinterpret_cast<const float4*>(&at[ty * 4 + 1][kq * 4]);
        const float4 a2 = *reinterpret_cast<const float4*>(&at[ty * 4 + 2][kq * 4]);
        const float4 a3 = *reinterpret_cast<const float4*>(&at[ty * 4 + 3][kq * 4]);
        s0 += a0.x * w4.x + a0.y * w4.y + a0.z * w4.z + a0.w * w4.w;
        s1 += a1.x * w4.x + a1.y * w4.y + a1.z * w4.z + a1.w * w4.w;
        s2 += a2.x * w4.x + a2.y * w4.y + a2.z * w4.z + a2.w * w4.w;
        s3 += a3.x * w4.x + a3.y * w4.y + a3.z * w4.z + a3.w * w4.w;
    }
    const float fb = fc1_b[o];
    float sv[4] = {s0, s1, s2, s3};
#pragma unroll
    for (int j = 0; j < 4; ++j) {
        const int bt  = bm * 32 + ty * 4 + j;
        const int row = (bt & 31) * 32 + (bt >> 5);
        out[row * 256 + o] = sv[j] + fb;
    }
}

extern "C" void kernel_launch(void* const* d_in, const int* in_sizes, int n_in,
                              void* d_out, int out_size, void* d_ws, size_t ws_size,
                              hipStream_t stream) {
    const float* inp   = (const float*)d_in[0];
    const float* ue_w  = (const float*)d_in[1];
    const float* ue_b  = (const float*)d_in[2];
    const float* be    = (const float*)d_in[3];
    const float* w_w   = (const float*)d_in[4];
    // d_in[5] = w_b: unused (softmax invariant to constant shift)
    const float* fc1_w = (const float*)d_in[6];
    const float* fc1_b = (const float*)d_in[7];
    float* out = (float*)d_out;

    const bool split = ws_size >= (size_t)1024 * 512 * 4;  // 2MB for attr
    if (split) {
        float* attr = (float*)d_ws;
        stattn_main<0><<<1024, 512, 0, stream>>>(inp, ue_w, ue_b, be, w_w,
                                                 fc1_w, fc1_b, attr);
        stattn_fc2<<<dim3(32, 8), 256, 0, stream>>>(attr, fc1_w, fc1_b, out);
    } else {
        stattn_main<1><<<1024, 512, 0, stream>>>(inp, ue_w, ue_b, be, w_w,
                                                 fc1_w, fc1_b, out);
    }
}